// Round 8
// baseline (543.166 us; speedup 1.0000x reference)
//
#include <hip/hip_runtime.h>
#include <stdint.h>

#define N_B    32768
#define MLPOUT 1056
#define MCAT_K 1216   // 1184 padded to 38*32
#define NPAD3  1280   // 1056 padded (W3t rows)

typedef __attribute__((ext_vector_type(8)))  __bf16 bf16x8;
typedef __attribute__((ext_vector_type(4)))  float  f32x4;
typedef __attribute__((ext_vector_type(16))) float  f32x16;

__device__ __forceinline__ uint16_t f2bf(float f){
  union { float f; uint32_t u; } v; v.f = f;
  return (uint16_t)((v.u + 0x7fffu + ((v.u >> 16) & 1u)) >> 16);
}
__device__ __forceinline__ float bf2f(uint16_t h){
  union { uint32_t u; float f; } v; v.u = ((uint32_t)h) << 16; return v.f;
}
__device__ __forceinline__ void gld_lds16(const void* gp, void* lp){
  __builtin_amdgcn_global_load_lds(
    (__attribute__((address_space(1))) void*)(void*)gp,
    (__attribute__((address_space(3))) void*)lp, 16, 0, 0);
}

// ---------------- k0a: f32 [K][N] -> bf16 [Npad][Kpad] transpose+cast+zero-pad ----------------
__global__ void transpose_cast_kernel(const float* __restrict__ in, uint16_t* __restrict__ out,
                                      int K, int N, int Kpad, int Npad)
{
  __shared__ float tile[32][33];
  const int tx = threadIdx.x & 31, ty = threadIdx.x >> 5;
  const int k0 = blockIdx.x * 32, n0 = blockIdx.y * 32;
#pragma unroll
  for (int i = 0; i < 4; i++){
    int k = k0 + ty + i*8, nn = n0 + tx;
    float v = (k < K && nn < N) ? in[(size_t)k*N + nn] : 0.0f;
    tile[ty + i*8][tx] = v;
  }
  __syncthreads();
#pragma unroll
  for (int i = 0; i < 4; i++){
    int nn = n0 + ty + i*8, k = k0 + tx;
    if (nn < Npad && k < Kpad) out[(size_t)nn*Kpad + k] = f2bf(tile[tx][ty + i*8]);
  }
}

// ---------------- k0b: fused W -> pre-packed MFMA B-fragments (hi/lo bf16) ----------------
__global__ void prep_small_kernel(const float* __restrict__ W_Z1, const float* __restrict__ W_Z2,
                                  const float* __restrict__ b3,
                                  uint16_t* __restrict__ WfH, uint16_t* __restrict__ WfL,
                                  float* __restrict__ wgG, float* __restrict__ b3p)
{
  __shared__ float wl[192*32];
  const int tid = threadIdx.x;
  for (int idx = tid; idx < 6144; idx += 256){
    int r = idx >> 5, c = idx & 31;
    float v;
    if (r < 64){
      v = 0.f;
      for (int i = 0; i < 32; i++) v += W_Z1[r*32 + i] * W_Z2[i*32 + c];
    } else v = W_Z2[(r - 32)*32 + c];
    wl[idx] = v;
  }
  __syncthreads();
  for (int q = tid; q < 768; q += 256){
    int lane = q & 63, ctkk = q >> 6;
    int ct = ctkk & 1, kk = ctkk >> 1;
    int c  = ct*16 + (lane & 15);
    int k0 = kk*32 + ((lane >> 4) << 3);
    for (int j = 0; j < 8; j++){
      float v = wl[(k0 + j)*32 + c];
      uint16_t hb = f2bf(v);
      WfH[q*8 + j] = hb;
      WfL[q*8 + j] = f2bf(v - bf2f(hb));
    }
  }
  if (tid < 32) wgG[tid] = W_Z2[160*32 + tid];
  for (int idx = tid; idx < NPAD3; idx += 256)
    b3p[idx] = (idx < MLPOUT) ? b3[idx] : 0.0f;
}

// ---------------- P1: h / hm / gate ----------------
__global__ __launch_bounds__(256)
void gate_kernel(const float* __restrict__ h0, const float* __restrict__ mh,
                 const float* __restrict__ W_h1, const float* __restrict__ b_h1,
                 const float* __restrict__ W_g1a, const float* __restrict__ b_g1a,
                 const float* __restrict__ W_g1b, const float* __restrict__ b_g1b,
                 uint16_t* __restrict__ Mcat, float* __restrict__ gateOut)
{
  __shared__ float wh[128*32];
  __shared__ float wg[160*32];
  __shared__ float wgb[32], bh[32], bga[32];
  __shared__ float bgb;
  __shared__ float hrow[4][128];
  __shared__ float hms[4][160];
  const int tid = threadIdx.x, w = tid >> 6, l = tid & 63;
  for (int i = tid; i < 4096; i += 256) wh[i] = W_h1[i];
  for (int i = tid; i < 5120; i += 256) wg[i] = W_g1a[i];
  if (tid < 32){ wgb[tid] = W_g1b[tid]; bh[tid] = b_h1[tid]; bga[tid] = b_g1a[tid]; }
  if (tid == 0) bgb = b_g1b[0];
  __syncthreads();
  const int cg = l & 31, kh = l >> 5;
  for (int bi = 0; bi < 16; bi++){
    const int b = blockIdx.x*64 + w*16 + bi;
    hrow[w][l]      = h0[(size_t)b*128 + l];
    hrow[w][64 + l] = h0[(size_t)b*128 + 64 + l];
    float mh0 = mh[(size_t)b*128 + l];
    float mh1 = mh[(size_t)b*128 + 64 + l];
    float hacc = 0.f;
#pragma unroll 16
    for (int i = 0; i < 64; i++){
      int k = kh*64 + i;
      hacc += hrow[w][k] * wh[k*32 + cg];
    }
    hacc += __shfl_xor(hacc, 32);
    float hmc = fmaxf(hacc + bh[cg], 0.f);
    float r0 = fmaxf(mh0, 0.f), r1 = fmaxf(mh1, 0.f);
    if (l < 32) hms[w][l] = hmc;
    hms[w][32 + l] = r0;
    hms[w][96 + l] = r1;
    uint16_t* mc = Mcat + (size_t)b*MCAT_K + 1024;
    if (l < 32) mc[l] = f2bf(hmc);
    mc[32 + l] = f2bf(r0);
    mc[96 + l] = f2bf(r1);
    if (l < 32) mc[160 + l] = 0;     // zero K-pad 1184..1215
    float tacc = 0.f;
#pragma unroll 16
    for (int i = 0; i < 80; i++){
      int k = kh*80 + i;
      tacc += hms[w][k] * wg[k*32 + cg];
    }
    tacc += __shfl_xor(tacc, 32);
    float tc = fmaxf(tacc + bga[cg], 0.f);
    float gp = (l < 32) ? tc * wgb[cg] : 0.f;
#pragma unroll
    for (int s = 1; s < 64; s <<= 1) gp += __shfl_xor(gp, s);
    if (l == 0) gateOut[b] = gp + bgb;
  }
}

// ---------------- P2: Zm (MFMA, compensated) + gram (MFMA) + F ----------------
__global__ __launch_bounds__(256)
void zm_gram_kernel(const float* __restrict__ Z0, const float* __restrict__ mZ,
                    const uint16_t* __restrict__ WfH, const uint16_t* __restrict__ WfL,
                    const float* __restrict__ wgG, const float* __restrict__ gateB,
                    uint16_t* __restrict__ Mcat, float* __restrict__ Fn,
                    float* __restrict__ ZmOut)
{
  __shared__ __align__(16) uint16_t wfh[6144], wfl[6144];
  __shared__ float wgs[32];
  __shared__ __align__(16) uint16_t zhS[4][32*24], zlS[4][32*24];
  const int tid = threadIdx.x, w = tid >> 6, l = tid & 63;
#pragma unroll
  for (int i = 0; i < 3; i++){
    gld_lds16(WfH + (i*256 + tid)*8, &wfh[(i*256 + w*64)*8]);
    gld_lds16(WfL + (i*256 + tid)*8, &wfl[(i*256 + w*64)*8]);
  }
  if (tid < 32) wgs[tid] = wgG[tid];
  __syncthreads();
  const int n = l & 15, sl = l >> 4;
  for (int bi = 0; bi < 4; bi++){
    const int b = (blockIdx.x << 4) + (w << 2) + bi;
    bf16x8 xh[6], xl[6];
    const float* zp = Z0 + (size_t)b*1024 + n*64  + sl*8;
    const float* mp = mZ + (size_t)b*2048 + n*128 + sl*8;
#pragma unroll
    for (int kk = 0; kk < 6; kk++){
      const float* src = (kk < 2) ? (zp + kk*32) : (mp + (kk - 2)*32);
      float x[8];
      *(float4*)&x[0] = *(const float4*)src;
      *(float4*)&x[4] = *(const float4*)(src + 4);
#pragma unroll
      for (int j = 0; j < 8; j++){
        __bf16 h = (__bf16)x[j];
        xh[kk][j] = h;
        xl[kk][j] = (__bf16)(x[j] - (float)h);
      }
    }
    f32x4 za[2];
    za[0] = (f32x4)(0.f); za[1] = (f32x4)(0.f);
#pragma unroll
    for (int kk = 0; kk < 6; kk++){
#pragma unroll
      for (int ct = 0; ct < 2; ct++){
        bf16x8 whf = *(const bf16x8*)&wfh[((kk*2 + ct)*64 + l)*8];
        bf16x8 wlf = *(const bf16x8*)&wfl[((kk*2 + ct)*64 + l)*8];
        za[ct] = __builtin_amdgcn_mfma_f32_16x16x32_bf16(xh[kk], whf, za[ct], 0, 0, 0);
        za[ct] = __builtin_amdgcn_mfma_f32_16x16x32_bf16(xl[kk], whf, za[ct], 0, 0, 0);
        za[ct] = __builtin_amdgcn_mfma_f32_16x16x32_bf16(xh[kk], wlf, za[ct], 0, 0, 0);
      }
    }
    const float g = gateB[b];
    if (sl == 0){
      za[0][2] += g * wgs[n];
      za[1][2] += g * wgs[16 + n];
    }
    float* zo = ZmOut + (size_t)b*512;
#pragma unroll
    for (int ct = 0; ct < 2; ct++){
      ushort4 ph, pl;
#pragma unroll
      for (int r = 0; r < 4; r++){
        float v = za[ct][r];
        zo[(sl*4 + r)*32 + ct*16 + n] = v;
        uint16_t hb = f2bf(v);
        ((uint16_t*)&ph)[r] = hb;
        ((uint16_t*)&pl)[r] = f2bf(v - bf2f(hb));
      }
      const int c = ct*16 + n;
      *(ushort4*)&zhS[w][c*24 + sl*4] = ph;
      *(ushort4*)&zlS[w][c*24 + sl*4] = pl;
    }
    const int c2 = l & 31, n0 = (l >> 5) << 3;
    bf16x8 zhf = *(const bf16x8*)&zhS[w][c2*24 + n0];
    bf16x8 zlf = *(const bf16x8*)&zlS[w][c2*24 + n0];
    f32x16 gacc = (f32x16)(0.f);
    gacc = __builtin_amdgcn_mfma_f32_32x32x16_bf16(zhf, zhf, gacc, 0, 0, 0);
    gacc = __builtin_amdgcn_mfma_f32_32x32x16_bf16(zlf, zhf, gacc, 0, 0, 0);
    gacc = __builtin_amdgcn_mfma_f32_32x32x16_bf16(zhf, zlf, gacc, 0, 0, 0);
    float fs = 0.f;
#pragma unroll
    for (int i = 0; i < 16; i++) fs += gacc[i]*gacc[i];
#pragma unroll
    for (int s = 1; s < 64; s <<= 1) fs += __shfl_xor(fs, s);
    if (l == 0) Fn[b] = sqrtf(fs) + 1.0f;
    uint16_t* mcb = Mcat + (size_t)b*MCAT_K;
#pragma unroll
    for (int r = 0; r < 16; r++){
      int row = (r & 3) + 8*(r >> 2) + 4*(l >> 5);
      mcb[row*32 + c2] = f2bf(gacc[r]);
    }
  }
}

// ---------------- 128x128 bf16 GEMM, 4 waves, quad-buffered BK=32, 2 blocks/CU ----------------
// r8 rationale: rounds 3-7 (512thr/128KB LDS = 1 barrier-domain per CU) all stuck at ~11k cyc
// per K64-tile regardless of schedule => all-wave VMEM wait with no co-resident work to hide it.
// This kernel: 64KB LDS => 2 independent blocks/CU; 3-step prefetch lead; per K32-step exactly
// {8 ds_read -> lgkm0 -> vmcnt(4 counted) -> s_barrier -> stage(t+3) -> 16 MFMA/wave}.
// Ledger: STAGE(s) issued at iter s-3 (post-BAR); confirmed at iter s-1 (vmcnt(4) pre-BAR;
// tail t==NT-2 uses vmcnt(0)); overwrite of slot (t+3)&3 == (t-1)&3 is post-BAR(t) while all
// reads of it were pre-BAR(t-1). Swizzle: 16B-chunk ^ (row&3); staged linear, source pre-swizzled.
template<int NT, int RELU, int MODE, int NTN>
__global__ __launch_bounds__(256, 2)
void gemmq_kernel(const uint16_t* __restrict__ A, const uint16_t* __restrict__ Bt,
                  const float* __restrict__ bias, uint16_t* __restrict__ outB,
                  float* __restrict__ outF, const float* __restrict__ Fn)
{
  constexpr int KK = NT * 32;
  __shared__ __align__(16) uint16_t lds[32768];   // 64 KiB: 4 slots x (A[128*32] + B[128*32])
  const int tid = threadIdx.x;
  const int w = tid >> 6, l = tid & 63;
  const int wr = w >> 1, wc = w & 1;
  const int lr = l & 15, kq = l >> 4;
  const int cs = ((kq ^ (lr & 3))) * 8;           // swizzled chunk offset (elems)
  // XCD-chunked bijective remap: consecutive tl on one XCD -> NTN blocks share A panel in L2
  const int cpx = 32 * NTN;                       // (256*NTN)/8
  const int tl  = (blockIdx.x & 7) * cpx + (blockIdx.x >> 3);
  const int m0  = (tl / NTN) * 128, n0 = (tl % NTN) * 128;

  f32x4 acc[4][4];
#pragma unroll
  for (int r = 0; r < 4; r++)
#pragma unroll
    for (int c = 0; c < 4; c++) acc[r][c] = (f32x4)(0.0f);
  bf16x8 af[4], bf[4];

#define STAGE(s_, kt_) do{ \
  _Pragma("unroll") for (int j_ = 0; j_ < 2; j_++){ \
    int sl_ = j_*256 + tid; int r_ = sl_ >> 2; int c_ = (sl_ & 3) ^ (r_ & 3); \
    gld_lds16(A  + (size_t)(m0 + r_)*KK + (kt_)*32 + c_*8, \
              &lds[(s_)*8192 + (j_*256 + w*64)*8]); } \
  _Pragma("unroll") for (int j_ = 0; j_ < 2; j_++){ \
    int sl_ = j_*256 + tid; int r_ = sl_ >> 2; int c_ = (sl_ & 3) ^ (r_ & 3); \
    gld_lds16(Bt + (size_t)(n0 + r_)*KK + (kt_)*32 + c_*8, \
              &lds[(s_)*8192 + 4096 + (j_*256 + w*64)*8]); } }while(0)
#define RDFRAGS(s_) do{ \
  _Pragma("unroll") for (int r_ = 0; r_ < 4; r_++){ \
    int R_ = wr*64 + r_*16 + lr; \
    af[r_] = *(const bf16x8*)&lds[(s_)*8192 + R_*32 + cs]; } \
  _Pragma("unroll") for (int c_ = 0; c_ < 4; c_++){ \
    int R_ = wc*64 + c_*16 + lr; \
    bf[c_] = *(const bf16x8*)&lds[(s_)*8192 + 4096 + R_*32 + cs]; } }while(0)
#define DOMFMA() do{ _Pragma("unroll") for (int r_ = 0; r_ < 4; r_++) \
  _Pragma("unroll") for (int c_ = 0; c_ < 4; c_++) \
    acc[r_][c_] = __builtin_amdgcn_mfma_f32_16x16x32_bf16(af[r_], bf[c_], acc[r_][c_], 0, 0, 0); \
  }while(0)

  // prologue: stage slots 0..2 (12 loads/wave), retire slot0 (<=8 left), barrier
  STAGE(0, 0); STAGE(1, 1); STAGE(2, 2);
  asm volatile("s_waitcnt vmcnt(8)" ::: "memory");
  asm volatile("s_barrier" ::: "memory");

#pragma unroll 1
  for (int t = 0; t < NT; t++){
    RDFRAGS(t & 3);
    asm volatile("s_waitcnt lgkmcnt(0)" ::: "memory");   // frags in regs (release half)
    if (t + 2 < NT) { asm volatile("s_waitcnt vmcnt(4)" ::: "memory"); }  // slot t+1 landed
    else            { asm volatile("s_waitcnt vmcnt(0)" ::: "memory"); }
    asm volatile("s_barrier" ::: "memory");              // acquire: slot t+1 visible to all
    if (t + 3 < NT) STAGE((t + 3) & 3, t + 3);           // overwrite slot (t-1)&3: safe
    DOMFMA();
  }
#undef STAGE
#undef RDFRAGS
#undef DOMFMA

  // epilogue: C/D col = l&15 (B-dim), row = (l>>4)*4 + i (A-dim)
#pragma unroll
  for (int c = 0; c < 4; c++){
    const int gcol = n0 + wc*64 + c*16 + lr;
    const float bv = bias[gcol];
#pragma unroll
    for (int r = 0; r < 4; r++){
      const int grow0 = m0 + wr*64 + r*16 + kq*4;
#pragma unroll
      for (int gg = 0; gg < 4; gg++){
        float v = acc[r][c][gg] + bv;
        if (RELU) v = fmaxf(v, 0.0f);
        const int grow = grow0 + gg;
        if (MODE == 0){
          outB[(size_t)grow*1024 + gcol] = f2bf(v);
        } else {
          if (gcol < 1024)      outB[(size_t)grow*1024 + gcol] = f2bf(v);
          else if (gcol < 1056) outF[(size_t)grow*32 + (gcol - 1024)] = v / Fn[grow];
        }
      }
    }
  }
}

// ---------------- k5: M_Z = (Zm @ M_Zflat) / F ----------------
__global__ __launch_bounds__(256)
void epilogue_kernel(const uint16_t* __restrict__ Mzf, const float* __restrict__ Fn,
                     float* __restrict__ Out)
{
  __shared__ __align__(16) uint16_t mzS[4][1024];
  __shared__ __align__(16) float    zmS[4][16*36];
  const int tid = threadIdx.x, w = tid >> 6, l = tid & 63;
  const int n = l & 15, q = l >> 4;
  for (int bi = 0; bi < 4; bi++){
    const int b = (blockIdx.x << 4) + (w << 2) + bi;
    const uint4* src = (const uint4*)(Mzf + (size_t)b*1024);
    uint4* dst = (uint4*)&mzS[w][0];
    dst[l]      = src[l];
    dst[l + 64] = src[l + 64];
    const float4* zsrc = (const float4*)(Out + (size_t)b*512);
#pragma unroll
    for (int i = 0; i < 2; i++){
      int f = i*64 + l;
      int nn = f >> 3, c4 = f & 7;
      *(float4*)&zmS[w][nn*36 + c4*4] = zsrc[f];
    }
    float acc[8];
#pragma unroll
    for (int i = 0; i < 8; i++) acc[i] = 0.f;
#pragma unroll
    for (int j = 0; j < 32; j++){
      float zv = zmS[w][n*36 + j];
      uint4 mv = *(const uint4*)&mzS[w][j*32 + q*8];
      acc[0] += zv * bf2f((uint16_t)(mv.x & 0xffffu));
      acc[1] += zv * bf2f((uint16_t)(mv.x >> 16));
      acc[2] += zv * bf2f((uint16_t)(mv.y & 0xffffu));
      acc[3] += zv * bf2f((uint16_t)(mv.y >> 16));
      acc[4] += zv * bf2f((uint16_t)(mv.z & 0xffffu));
      acc[5] += zv * bf2f((uint16_t)(mv.z >> 16));
      acc[6] += zv * bf2f((uint16_t)(mv.w & 0xffffu));
      acc[7] += zv * bf2f((uint16_t)(mv.w >> 16));
    }
    const float inv = 1.0f / Fn[b];
    float4* op = (float4*)(Out + (size_t)b*512 + n*32 + q*8);
    op[0] = make_float4(acc[0]*inv, acc[1]*inv, acc[2]*inv, acc[3]*inv);
    op[1] = make_float4(acc[4]*inv, acc[5]*inv, acc[6]*inv, acc[7]*inv);
  }
}

// ---------------- launch ----------------
extern "C" void kernel_launch(void* const* d_in, const int* in_sizes, int n_in,
                              void* d_out, int out_size, void* d_ws, size_t ws_size,
                              hipStream_t stream)
{
  const float* Z0    = (const float*)d_in[0];
  const float* h0    = (const float*)d_in[1];
  const float* mZ    = (const float*)d_in[2];
  const float* mh    = (const float*)d_in[3];
  const float* W_Z1  = (const float*)d_in[4];
  const float* W_h1  = (const float*)d_in[5];
  const float* b_h1  = (const float*)d_in[6];
  const float* W_g1a = (const float*)d_in[7];
  const float* b_g1a = (const float*)d_in[8];
  const float* W_g1b = (const float*)d_in[9];
  const float* b_g1b = (const float*)d_in[10];
  const float* W_Z2  = (const float*)d_in[11];
  const float* W1    = (const float*)d_in[12];
  const float* b1    = (const float*)d_in[13];
  const float* W2    = (const float*)d_in[14];
  const float* b2    = (const float*)d_in[15];
  const float* W3    = (const float*)d_in[16];
  const float* b3    = (const float*)d_in[17];

  char* ws = (char*)d_ws;
  size_t off = 0;
  auto alloc = [&](size_t bytes) -> char* {
    char* p = ws + off;
    off += (bytes + 255) & ~(size_t)255;
    return p;
  };
  uint16_t* W1t  = (uint16_t*)alloc((size_t)1024*MCAT_K*2);
  uint16_t* W2t  = (uint16_t*)alloc((size_t)1024*1024*2);
  uint16_t* W3t  = (uint16_t*)alloc((size_t)NPAD3*1024*2);
  float*    b3p  = (float*)   alloc((size_t)NPAD3*4);
  uint16_t* WfH  = (uint16_t*)alloc((size_t)6144*2);
  uint16_t* WfL  = (uint16_t*)alloc((size_t)6144*2);
  float*    wgG  = (float*)   alloc((size_t)32*4);
  float*    gate = (float*)   alloc((size_t)N_B*4);
  float*    Fn   = (float*)   alloc((size_t)N_B*4);
  uint16_t* Mcat = (uint16_t*)alloc((size_t)N_B*MCAT_K*2);
  uint16_t* H1   = (uint16_t*)alloc((size_t)N_B*1024*2);
  uint16_t* H2   = (uint16_t*)alloc((size_t)N_B*1024*2);
  uint16_t* Mzf  = Mcat;                          // Mcat dead after GEMM1 -> reuse (stride 1024)
  float* OutMZ = (float*)d_out;
  float* OutMH = (float*)d_out + (size_t)N_B*512;

  transpose_cast_kernel<<<dim3(38,32), 256, 0, stream>>>(W1, W1t, 1184, 1024, MCAT_K, 1024);
  transpose_cast_kernel<<<dim3(32,32), 256, 0, stream>>>(W2, W2t, 1024, 1024, 1024, 1024);
  transpose_cast_kernel<<<dim3(32,40), 256, 0, stream>>>(W3, W3t, 1024, 1056, 1024, NPAD3);
  prep_small_kernel<<<1, 256, 0, stream>>>(W_Z1, W_Z2, b3, WfH, WfL, wgG, b3p);
  gate_kernel<<<512, 256, 0, stream>>>(h0, mh, W_h1, b_h1, W_g1a, b_g1a, W_g1b, b_g1b,
                                       Mcat, gate);
  zm_gram_kernel<<<2048, 256, 0, stream>>>(Z0, mZ, WfH, WfL, wgG, gate, Mcat, Fn, OutMZ);
  gemmq_kernel<38,1,0,8><<<2048, 256, 0, stream>>>(Mcat, W1t, b1, H1, nullptr, nullptr);
  gemmq_kernel<32,1,0,8><<<2048, 256, 0, stream>>>(H1,   W2t, b2, H2, nullptr, nullptr);
  gemmq_kernel<32,0,1,9><<<2304, 256, 0, stream>>>(H2,   W3t, b3p, Mzf, OutMH, Fn);
  epilogue_kernel<<<2048, 256, 0, stream>>>(Mzf, Fn, OutMZ);
}

// Round 11
// 531.592 us; speedup vs baseline: 1.0218x; 1.0218x over previous
//
#include <hip/hip_runtime.h>
#include <stdint.h>

#define N_B    32768
#define MLPOUT 1056
#define MCAT_K 1216   // 1184 padded to 19*64
#define NPAD3  1280   // 1056 padded (W3t rows)

typedef __attribute__((ext_vector_type(8)))  __bf16 bf16x8;
typedef __attribute__((ext_vector_type(4)))  float  f32x4;
typedef __attribute__((ext_vector_type(16))) float  f32x16;

__device__ __forceinline__ uint16_t f2bf(float f){
  union { float f; uint32_t u; } v; v.f = f;
  return (uint16_t)((v.u + 0x7fffu + ((v.u >> 16) & 1u)) >> 16);
}
__device__ __forceinline__ float bf2f(uint16_t h){
  union { uint32_t u; float f; } v; v.u = ((uint32_t)h) << 16; return v.f;
}
__device__ __forceinline__ void gld_lds16(const void* gp, void* lp){
  __builtin_amdgcn_global_load_lds(
    (__attribute__((address_space(1))) void*)(void*)gp,
    (__attribute__((address_space(3))) void*)lp, 16, 0, 0);
}

// ---------------- k0a: f32 [K][N] -> bf16 [Npad][Kpad] transpose+cast+zero-pad ----------------
__global__ void transpose_cast_kernel(const float* __restrict__ in, uint16_t* __restrict__ out,
                                      int K, int N, int Kpad, int Npad)
{
  __shared__ float tile[32][33];
  const int tx = threadIdx.x & 31, ty = threadIdx.x >> 5;
  const int k0 = blockIdx.x * 32, n0 = blockIdx.y * 32;
#pragma unroll
  for (int i = 0; i < 4; i++){
    int k = k0 + ty + i*8, nn = n0 + tx;
    float v = (k < K && nn < N) ? in[(size_t)k*N + nn] : 0.0f;
    tile[ty + i*8][tx] = v;
  }
  __syncthreads();
#pragma unroll
  for (int i = 0; i < 4; i++){
    int nn = n0 + ty + i*8, k = k0 + tx;
    if (nn < Npad && k < Kpad) out[(size_t)nn*Kpad + k] = f2bf(tile[tx][ty + i*8]);
  }
}

// ---------------- k0b: fused W -> pre-packed MFMA B-fragments (hi/lo bf16) ----------------
__global__ void prep_small_kernel(const float* __restrict__ W_Z1, const float* __restrict__ W_Z2,
                                  const float* __restrict__ b3,
                                  uint16_t* __restrict__ WfH, uint16_t* __restrict__ WfL,
                                  float* __restrict__ wgG, float* __restrict__ b3p)
{
  __shared__ float wl[192*32];
  const int tid = threadIdx.x;
  for (int idx = tid; idx < 6144; idx += 256){
    int r = idx >> 5, c = idx & 31;
    float v;
    if (r < 64){
      v = 0.f;
      for (int i = 0; i < 32; i++) v += W_Z1[r*32 + i] * W_Z2[i*32 + c];
    } else v = W_Z2[(r - 32)*32 + c];
    wl[idx] = v;
  }
  __syncthreads();
  for (int q = tid; q < 768; q += 256){
    int lane = q & 63, ctkk = q >> 6;
    int ct = ctkk & 1, kk = ctkk >> 1;
    int c  = ct*16 + (lane & 15);
    int k0 = kk*32 + ((lane >> 4) << 3);
    for (int j = 0; j < 8; j++){
      float v = wl[(k0 + j)*32 + c];
      uint16_t hb = f2bf(v);
      WfH[q*8 + j] = hb;
      WfL[q*8 + j] = f2bf(v - bf2f(hb));
    }
  }
  if (tid < 32) wgG[tid] = W_Z2[160*32 + tid];
  for (int idx = tid; idx < NPAD3; idx += 256)
    b3p[idx] = (idx < MLPOUT) ? b3[idx] : 0.0f;
}

// ---------------- P1: h / hm / gate ----------------
__global__ __launch_bounds__(256)
void gate_kernel(const float* __restrict__ h0, const float* __restrict__ mh,
                 const float* __restrict__ W_h1, const float* __restrict__ b_h1,
                 const float* __restrict__ W_g1a, const float* __restrict__ b_g1a,
                 const float* __restrict__ W_g1b, const float* __restrict__ b_g1b,
                 uint16_t* __restrict__ Mcat, float* __restrict__ gateOut)
{
  __shared__ float wh[128*32];
  __shared__ float wg[160*32];
  __shared__ float wgb[32], bh[32], bga[32];
  __shared__ float bgb;
  __shared__ float hrow[4][128];
  __shared__ float hms[4][160];
  const int tid = threadIdx.x, w = tid >> 6, l = tid & 63;
  for (int i = tid; i < 4096; i += 256) wh[i] = W_h1[i];
  for (int i = tid; i < 5120; i += 256) wg[i] = W_g1a[i];
  if (tid < 32){ wgb[tid] = W_g1b[tid]; bh[tid] = b_h1[tid]; bga[tid] = b_g1a[tid]; }
  if (tid == 0) bgb = b_g1b[0];
  __syncthreads();
  const int cg = l & 31, kh = l >> 5;
  for (int bi = 0; bi < 16; bi++){
    const int b = blockIdx.x*64 + w*16 + bi;
    hrow[w][l]      = h0[(size_t)b*128 + l];
    hrow[w][64 + l] = h0[(size_t)b*128 + 64 + l];
    float mh0 = mh[(size_t)b*128 + l];
    float mh1 = mh[(size_t)b*128 + 64 + l];
    float hacc = 0.f;
#pragma unroll 16
    for (int i = 0; i < 64; i++){
      int k = kh*64 + i;
      hacc += hrow[w][k] * wh[k*32 + cg];
    }
    hacc += __shfl_xor(hacc, 32);
    float hmc = fmaxf(hacc + bh[cg], 0.f);
    float r0 = fmaxf(mh0, 0.f), r1 = fmaxf(mh1, 0.f);
    if (l < 32) hms[w][l] = hmc;
    hms[w][32 + l] = r0;
    hms[w][96 + l] = r1;
    uint16_t* mc = Mcat + (size_t)b*MCAT_K + 1024;
    if (l < 32) mc[l] = f2bf(hmc);
    mc[32 + l] = f2bf(r0);
    mc[96 + l] = f2bf(r1);
    if (l < 32) mc[160 + l] = 0;     // zero K-pad 1184..1215
    float tacc = 0.f;
#pragma unroll 16
    for (int i = 0; i < 80; i++){
      int k = kh*80 + i;
      tacc += hms[w][k] * wg[k*32 + cg];
    }
    tacc += __shfl_xor(tacc, 32);
    float tc = fmaxf(tacc + bga[cg], 0.f);
    float gp = (l < 32) ? tc * wgb[cg] : 0.f;
#pragma unroll
    for (int s = 1; s < 64; s <<= 1) gp += __shfl_xor(gp, s);
    if (l == 0) gateOut[b] = gp + bgb;
  }
}

// ---------------- P2: Zm (MFMA, compensated) + gram (MFMA) + F ----------------
__global__ __launch_bounds__(256)
void zm_gram_kernel(const float* __restrict__ Z0, const float* __restrict__ mZ,
                    const uint16_t* __restrict__ WfH, const uint16_t* __restrict__ WfL,
                    const float* __restrict__ wgG, const float* __restrict__ gateB,
                    uint16_t* __restrict__ Mcat, float* __restrict__ Fn,
                    float* __restrict__ ZmOut)
{
  __shared__ __align__(16) uint16_t wfh[6144], wfl[6144];
  __shared__ float wgs[32];
  __shared__ __align__(16) uint16_t zhS[4][32*24], zlS[4][32*24];
  const int tid = threadIdx.x, w = tid >> 6, l = tid & 63;
#pragma unroll
  for (int i = 0; i < 3; i++){
    gld_lds16(WfH + (i*256 + tid)*8, &wfh[(i*256 + w*64)*8]);
    gld_lds16(WfL + (i*256 + tid)*8, &wfl[(i*256 + w*64)*8]);
  }
  if (tid < 32) wgs[tid] = wgG[tid];
  asm volatile("s_waitcnt vmcnt(0)" ::: "memory");   // LDS-DMA not drained by __syncthreads (r10 lesson)
  __syncthreads();
  const int n = l & 15, sl = l >> 4;
  for (int bi = 0; bi < 4; bi++){
    const int b = (blockIdx.x << 4) + (w << 2) + bi;
    bf16x8 xh[6], xl[6];
    const float* zp = Z0 + (size_t)b*1024 + n*64  + sl*8;
    const float* mp = mZ + (size_t)b*2048 + n*128 + sl*8;
#pragma unroll
    for (int kk = 0; kk < 6; kk++){
      const float* src = (kk < 2) ? (zp + kk*32) : (mp + (kk - 2)*32);
      float x[8];
      *(float4*)&x[0] = *(const float4*)src;
      *(float4*)&x[4] = *(const float4*)(src + 4);
#pragma unroll
      for (int j = 0; j < 8; j++){
        __bf16 h = (__bf16)x[j];
        xh[kk][j] = h;
        xl[kk][j] = (__bf16)(x[j] - (float)h);
      }
    }
    f32x4 za[2];
    za[0] = (f32x4)(0.f); za[1] = (f32x4)(0.f);
#pragma unroll
    for (int kk = 0; kk < 6; kk++){
#pragma unroll
      for (int ct = 0; ct < 2; ct++){
        bf16x8 whf = *(const bf16x8*)&wfh[((kk*2 + ct)*64 + l)*8];
        bf16x8 wlf = *(const bf16x8*)&wfl[((kk*2 + ct)*64 + l)*8];
        za[ct] = __builtin_amdgcn_mfma_f32_16x16x32_bf16(xh[kk], whf, za[ct], 0, 0, 0);
        za[ct] = __builtin_amdgcn_mfma_f32_16x16x32_bf16(xl[kk], whf, za[ct], 0, 0, 0);
        za[ct] = __builtin_amdgcn_mfma_f32_16x16x32_bf16(xh[kk], wlf, za[ct], 0, 0, 0);
      }
    }
    const float g = gateB[b];
    if (sl == 0){
      za[0][2] += g * wgs[n];
      za[1][2] += g * wgs[16 + n];
    }
    float* zo = ZmOut + (size_t)b*512;
#pragma unroll
    for (int ct = 0; ct < 2; ct++){
      ushort4 ph, pl;
#pragma unroll
      for (int r = 0; r < 4; r++){
        float v = za[ct][r];
        zo[(sl*4 + r)*32 + ct*16 + n] = v;
        uint16_t hb = f2bf(v);
        ((uint16_t*)&ph)[r] = hb;
        ((uint16_t*)&pl)[r] = f2bf(v - bf2f(hb));
      }
      const int c = ct*16 + n;
      *(ushort4*)&zhS[w][c*24 + sl*4] = ph;
      *(ushort4*)&zlS[w][c*24 + sl*4] = pl;
    }
    const int c2 = l & 31, n0 = (l >> 5) << 3;
    bf16x8 zhf = *(const bf16x8*)&zhS[w][c2*24 + n0];
    bf16x8 zlf = *(const bf16x8*)&zlS[w][c2*24 + n0];
    f32x16 gacc = (f32x16)(0.f);
    gacc = __builtin_amdgcn_mfma_f32_32x32x16_bf16(zhf, zhf, gacc, 0, 0, 0);
    gacc = __builtin_amdgcn_mfma_f32_32x32x16_bf16(zlf, zhf, gacc, 0, 0, 0);
    gacc = __builtin_amdgcn_mfma_f32_32x32x16_bf16(zhf, zlf, gacc, 0, 0, 0);
    float fs = 0.f;
#pragma unroll
    for (int i = 0; i < 16; i++) fs += gacc[i]*gacc[i];
#pragma unroll
    for (int s = 1; s < 64; s <<= 1) fs += __shfl_xor(fs, s);
    if (l == 0) Fn[b] = sqrtf(fs) + 1.0f;
    uint16_t* mcb = Mcat + (size_t)b*MCAT_K;
#pragma unroll
    for (int r = 0; r < 16; r++){
      int row = (r & 3) + 8*(r >> 2) + 4*(l >> 5);
      mcb[row*32 + c2] = f2bf(gacc[r]);
    }
  }
}

// ---------------- 128x128 bf16 GEMM, BK=64 per phase, one sync + EXPLICIT vmcnt drain ----------------
// r11: r10's gemmk64 + asm vmcnt(0) BEFORE every __syncthreads. r9/r10 failure root cause:
// __syncthreads' workgroup fence does NOT drain vmcnt for LDS-DMA (global_load_lds writes LDS
// but is tracked by vmcnt) => iter t+1's ds_reads raced the in-flight stage of tile t+1.
// Ledger: sync@t = [vmcnt(0): stage(t+1) landed] + barrier => reads@t+1 safe; STAGE(s,t+2)
// post-barrier overwrites slot s whose reads all completed pre-barrier (data-dep drained).
template<int NT, int RELU, int MODE, int NTN>
__global__ __launch_bounds__(256, 2)
void gemmk64_kernel(const uint16_t* __restrict__ A, const uint16_t* __restrict__ Bt,
                    const float* __restrict__ bias, uint16_t* __restrict__ outB,
                    float* __restrict__ outF, const float* __restrict__ Fn)
{
  constexpr int KK = NT * 64;
  __shared__ __align__(16) uint16_t lds[32768];   // 64 KiB: 2 slots x (A[128*64] + B[128*64])
  const int tid = threadIdx.x;
  const int w = tid >> 6, l = tid & 63;
  const int wr = w >> 1, wc = w & 1;
  const int lr = l & 15, kq = l >> 4;
  const int cs0 = ((kq)     ^ (lr & 7)) * 8;
  const int cs1 = ((4 + kq) ^ (lr & 7)) * 8;
  const int cpx = 32 * NTN;                       // blocks per XCD = (256*NTN)/8
  const int tl  = (blockIdx.x & 7) * cpx + (blockIdx.x >> 3);
  const int m0  = (tl / NTN) * 128, n0 = (tl % NTN) * 128;

  f32x4 acc[4][4];
#pragma unroll
  for (int r = 0; r < 4; r++)
#pragma unroll
    for (int c = 0; c < 4; c++) acc[r][c] = (f32x4)(0.0f);
  bf16x8 af[4][2], bf[4][2];

#define STAGE(s_, kt_) do{ \
  _Pragma("unroll") for (int j_ = 0; j_ < 4; j_++){ \
    int sl_ = j_*256 + tid; int r_ = sl_ >> 3; int c_ = (sl_ & 7) ^ (r_ & 7); \
    gld_lds16(A  + (size_t)(m0 + r_)*KK + (kt_)*64 + c_*8, \
              &lds[(s_)*16384 + (j_*256 + w*64)*8]); } \
  _Pragma("unroll") for (int j_ = 0; j_ < 4; j_++){ \
    int sl_ = j_*256 + tid; int r_ = sl_ >> 3; int c_ = (sl_ & 7) ^ (r_ & 7); \
    gld_lds16(Bt + (size_t)(n0 + r_)*KK + (kt_)*64 + c_*8, \
              &lds[(s_)*16384 + 8192 + (j_*256 + w*64)*8]); } }while(0)
#define RDFRAGS(s_) do{ \
  _Pragma("unroll") for (int r_ = 0; r_ < 4; r_++){ \
    int R_ = (wr*64 + r_*16 + lr) * 64; \
    af[r_][0] = *(const bf16x8*)&lds[(s_)*16384 + R_ + cs0]; \
    af[r_][1] = *(const bf16x8*)&lds[(s_)*16384 + R_ + cs1]; } \
  _Pragma("unroll") for (int c_ = 0; c_ < 4; c_++){ \
    int R_ = (wc*64 + c_*16 + lr) * 64; \
    bf[c_][0] = *(const bf16x8*)&lds[(s_)*16384 + 8192 + R_ + cs0]; \
    bf[c_][1] = *(const bf16x8*)&lds[(s_)*16384 + 8192 + R_ + cs1]; } }while(0)
#define DOMFMA() do{ _Pragma("unroll") for (int r_ = 0; r_ < 4; r_++) \
  _Pragma("unroll") for (int c_ = 0; c_ < 4; c_++){ \
    acc[r_][c_] = __builtin_amdgcn_mfma_f32_16x16x32_bf16(af[r_][0], bf[c_][0], acc[r_][c_], 0, 0, 0); \
    acc[r_][c_] = __builtin_amdgcn_mfma_f32_16x16x32_bf16(af[r_][1], bf[c_][1], acc[r_][c_], 0, 0, 0); } \
  }while(0)
#define VMDRAIN() asm volatile("s_waitcnt vmcnt(0)" ::: "memory")

  STAGE(0, 0);
  STAGE(1, 1);
  VMDRAIN();                         // both prologue tiles landed in LDS
  __syncthreads();

#pragma unroll 1
  for (int t = 0; t < NT; t++){
    const int s = t & 1;
    RDFRAGS(s);
    DOMFMA();
    VMDRAIN();                       // stage(t+1) landed (LDS-DMA NOT covered by __syncthreads)
    __syncthreads();
    if (t + 2 < NT) STAGE(s, t + 2); // overwrite just-consumed slot
  }
#undef STAGE
#undef RDFRAGS
#undef DOMFMA
#undef VMDRAIN

  // epilogue: C/D col = l&15 (B-dim), row = (l>>4)*4 + i (A-dim)
#pragma unroll
  for (int c = 0; c < 4; c++){
    const int gcol = n0 + wc*64 + c*16 + lr;
    const float bv = bias[gcol];
#pragma unroll
    for (int r = 0; r < 4; r++){
      const int grow0 = m0 + wr*64 + r*16 + kq*4;
#pragma unroll
      for (int gg = 0; gg < 4; gg++){
        float v = acc[r][c][gg] + bv;
        if (RELU) v = fmaxf(v, 0.0f);
        const int grow = grow0 + gg;
        if (MODE == 0){
          outB[(size_t)grow*1024 + gcol] = f2bf(v);
        } else {
          if (gcol < 1024)      outB[(size_t)grow*1024 + gcol] = f2bf(v);
          else if (gcol < 1056) outF[(size_t)grow*32 + (gcol - 1024)] = v / Fn[grow];
        }
      }
    }
  }
}

// ---------------- k5: M_Z = (Zm @ M_Zflat) / F ----------------
__global__ __launch_bounds__(256)
void epilogue_kernel(const uint16_t* __restrict__ Mzf, const float* __restrict__ Fn,
                     float* __restrict__ Out)
{
  __shared__ __align__(16) uint16_t mzS[4][1024];
  __shared__ __align__(16) float    zmS[4][16*36];
  const int tid = threadIdx.x, w = tid >> 6, l = tid & 63;
  const int n = l & 15, q = l >> 4;
  for (int bi = 0; bi < 4; bi++){
    const int b = (blockIdx.x << 4) + (w << 2) + bi;
    const uint4* src = (const uint4*)(Mzf + (size_t)b*1024);
    uint4* dst = (uint4*)&mzS[w][0];
    dst[l]      = src[l];
    dst[l + 64] = src[l + 64];
    const float4* zsrc = (const float4*)(Out + (size_t)b*512);
#pragma unroll
    for (int i = 0; i < 2; i++){
      int f = i*64 + l;
      int nn = f >> 3, c4 = f & 7;
      *(float4*)&zmS[w][nn*36 + c4*4] = zsrc[f];
    }
    float acc[8];
#pragma unroll
    for (int i = 0; i < 8; i++) acc[i] = 0.f;
#pragma unroll
    for (int j = 0; j < 32; j++){
      float zv = zmS[w][n*36 + j];
      uint4 mv = *(const uint4*)&mzS[w][j*32 + q*8];
      acc[0] += zv * bf2f((uint16_t)(mv.x & 0xffffu));
      acc[1] += zv * bf2f((uint16_t)(mv.x >> 16));
      acc[2] += zv * bf2f((uint16_t)(mv.y & 0xffffu));
      acc[3] += zv * bf2f((uint16_t)(mv.y >> 16));
      acc[4] += zv * bf2f((uint16_t)(mv.z & 0xffffu));
      acc[5] += zv * bf2f((uint16_t)(mv.z >> 16));
      acc[6] += zv * bf2f((uint16_t)(mv.w & 0xffffu));
      acc[7] += zv * bf2f((uint16_t)(mv.w >> 16));
    }
    const float inv = 1.0f / Fn[b];
    float4* op = (float4*)(Out + (size_t)b*512 + n*32 + q*8);
    op[0] = make_float4(acc[0]*inv, acc[1]*inv, acc[2]*inv, acc[3]*inv);
    op[1] = make_float4(acc[4]*inv, acc[5]*inv, acc[6]*inv, acc[7]*inv);
  }
}

// ---------------- launch ----------------
extern "C" void kernel_launch(void* const* d_in, const int* in_sizes, int n_in,
                              void* d_out, int out_size, void* d_ws, size_t ws_size,
                              hipStream_t stream)
{
  const float* Z0    = (const float*)d_in[0];
  const float* h0    = (const float*)d_in[1];
  const float* mZ    = (const float*)d_in[2];
  const float* mh    = (const float*)d_in[3];
  const float* W_Z1  = (const float*)d_in[4];
  const float* W_h1  = (const float*)d_in[5];
  const float* b_h1  = (const float*)d_in[6];
  const float* W_g1a = (const float*)d_in[7];
  const float* b_g1a = (const float*)d_in[8];
  const float* W_g1b = (const float*)d_in[9];
  const float* b_g1b = (const float*)d_in[10];
  const float* W_Z2  = (const float*)d_in[11];
  const float* W1    = (const float*)d_in[12];
  const float* b1    = (const float*)d_in[13];
  const float* W2    = (const float*)d_in[14];
  const float* b2    = (const float*)d_in[15];
  const float* W3    = (const float*)d_in[16];
  const float* b3    = (const float*)d_in[17];

  char* ws = (char*)d_ws;
  size_t off = 0;
  auto alloc = [&](size_t bytes) -> char* {
    char* p = ws + off;
    off += (bytes + 255) & ~(size_t)255;
    return p;
  };
  uint16_t* W1t  = (uint16_t*)alloc((size_t)1024*MCAT_K*2);
  uint16_t* W2t  = (uint16_t*)alloc((size_t)1024*1024*2);
  uint16_t* W3t  = (uint16_t*)alloc((size_t)NPAD3*1024*2);
  float*    b3p  = (float*)   alloc((size_t)NPAD3*4);
  uint16_t* WfH  = (uint16_t*)alloc((size_t)6144*2);
  uint16_t* WfL  = (uint16_t*)alloc((size_t)6144*2);
  float*    wgG  = (float*)   alloc((size_t)32*4);
  float*    gate = (float*)   alloc((size_t)N_B*4);
  float*    Fn   = (float*)   alloc((size_t)N_B*4);
  uint16_t* Mcat = (uint16_t*)alloc((size_t)N_B*MCAT_K*2);
  uint16_t* H1   = (uint16_t*)alloc((size_t)N_B*1024*2);
  uint16_t* H2   = (uint16_t*)alloc((size_t)N_B*1024*2);
  uint16_t* Mzf  = Mcat;                          // Mcat dead after GEMM1 -> reuse (stride 1024)
  float* OutMZ = (float*)d_out;
  float* OutMH = (float*)d_out + (size_t)N_B*512;

  transpose_cast_kernel<<<dim3(38,32), 256, 0, stream>>>(W1, W1t, 1184, 1024, MCAT_K, 1024);
  transpose_cast_kernel<<<dim3(32,32), 256, 0, stream>>>(W2, W2t, 1024, 1024, 1024, 1024);
  transpose_cast_kernel<<<dim3(32,40), 256, 0, stream>>>(W3, W3t, 1024, 1056, 1024, NPAD3);
  prep_small_kernel<<<1, 256, 0, stream>>>(W_Z1, W_Z2, b3, WfH, WfL, wgG, b3p);
  gate_kernel<<<512, 256, 0, stream>>>(h0, mh, W_h1, b_h1, W_g1a, b_g1a, W_g1b, b_g1b,
                                       Mcat, gate);
  zm_gram_kernel<<<2048, 256, 0, stream>>>(Z0, mZ, WfH, WfL, wgG, gate, Mcat, Fn, OutMZ);
  gemmk64_kernel<19,1,0,8><<<2048, 256, 0, stream>>>(Mcat, W1t, b1, H1, nullptr, nullptr);
  gemmk64_kernel<16,1,0,8><<<2048, 256, 0, stream>>>(H1,   W2t, b2, H2, nullptr, nullptr);
  gemmk64_kernel<16,0,1,9><<<2304, 256, 0, stream>>>(H2,   W3t, b3p, Mzf, OutMH, Fn);
  epilogue_kernel<<<2048, 256, 0, stream>>>(Mzf, Fn, OutMZ);
}